// Round 1
// baseline (1677.576 us; speedup 1.0000x reference)
//
#include <hip/hip_runtime.h>
#include <math.h>

// ---------------------------------------------------------------------------
// VariableRVQ: 4-layer residual VQ, N=131072, D=128, K={1024,1024,512,512}
// d_out layout (floats): [quantized 131072*128][indices 131072*4][loss 4][perp 4][mse 4]
// ---------------------------------------------------------------------------

#define N_ROWS 131072
#define DDIM 128
#define BN 128            // rows per block
#define NTHREADS 256

#define OQ 0
#define OI 16777216
#define OL 17301504
#define OP 17301508
#define OM 17301512

// XOR swizzle on bits 2..4 of the minor index, keyed by d>>2: keeps float4
// groups contiguous/aligned while spreading banks for strided LDS writes.
__device__ __forceinline__ int rsw_(int d, int r) { return r ^ (((d >> 2) & 7) << 2); }

// ---------------------------------------------------------------------------
// codebook row norms: one wave per row
__global__ void cbnorm_kernel(const float* __restrict__ cb,
                              float* __restrict__ norms, int K)
{
    const int row  = blockIdx.x * 4 + (threadIdx.x >> 6);
    const int lane = threadIdx.x & 63;
    const float2 v = *(const float2*)(cb + (size_t)row * DDIM + lane * 2);
    float s = fmaf(v.x, v.x, v.y * v.y);
#pragma unroll
    for (int o = 32; o; o >>= 1) s += __shfl_xor(s, o);
    if (lane == 0) norms[row] = s;
}

// ---------------------------------------------------------------------------
// Fused: distance GEMM + argmin + gather + residual update + sumsq + histogram
template<bool LAST>
__global__ __launch_bounds__(256, 1)
void vq_layer_kernel(const float* res_in,            // [N,128] layer input residual
                     const float* __restrict__ cb,   // [K,128]
                     const float* __restrict__ cbnorm, // [K]
                     const int K,
                     const float* __restrict__ x,    // original input (LAST only)
                     float*       res_out,           // [N,128] residual out / qout (LAST)
                     float* __restrict__ idx_out,    // indices region of d_out
                     const int layer,
                     int*   __restrict__ hist,       // [K] this layer's bins
                     float* __restrict__ sumsq)      // [4]
{
    extern __shared__ float lds[];
    float* Rs = lds;               // [128 d][128 r] transposed+swizzled residual, 64KB
    float* Es = lds + 128 * 128;   // 2 x [64 dl][128 c] transposed+swizzled cb, 64KB

    const int tid = threadIdx.x;
    const int tx  = tid & 15, ty = tid >> 4;
    const int ty8 = ty << 3, tx4 = tx << 2;
    const int n0  = blockIdx.x * BN;

    // ---- stage residual tile: global row-major -> LDS [d][r] swizzled ----
    {
        const float* src = res_in + (size_t)n0 * DDIM;
#pragma unroll
        for (int v = 0; v < 16; ++v) {
            const int flat = (v * NTHREADS + tid) * 4;
            const int r  = flat >> 7;
            const int d0 = flat & 127;
            const float4 f = *(const float4*)(src + r * DDIM + d0);
            Rs[(d0 + 0) * 128 + rsw_(d0 + 0, r)] = f.x;
            Rs[(d0 + 1) * 128 + rsw_(d0 + 1, r)] = f.y;
            Rs[(d0 + 2) * 128 + rsw_(d0 + 2, r)] = f.z;
            Rs[(d0 + 3) * 128 + rsw_(d0 + 3, r)] = f.w;
        }
    }
    // ---- stage first codebook half (chunk 0, h 0) into buffer 0 ----
    {
#pragma unroll
        for (int v = 0; v < 8; ++v) {
            const int c  = v * 16 + ty;
            const int d0 = tx4;                       // local d within half
            const float4 f = *(const float4*)(cb + (size_t)c * DDIM + d0);
            Es[(d0 + 0) * 128 + rsw_(d0 + 0, c)] = f.x;
            Es[(d0 + 1) * 128 + rsw_(d0 + 1, c)] = f.y;
            Es[(d0 + 2) * 128 + rsw_(d0 + 2, c)] = f.z;
            Es[(d0 + 3) * 128 + rsw_(d0 + 3, c)] = f.w;
        }
    }
    __syncthreads();

    float minv[8];
    int   mink[8];
#pragma unroll
    for (int i = 0; i < 8; ++i) { minv[i] = 3.4e38f; mink[i] = 0; }

    const int nchunks = K >> 7;      // K/128 column chunks
    const int nh = nchunks * 2;      // half-tiles of 64 d

    float acc[8][8];

    for (int hh = 0; hh < nh; ++hh) {
        const int chunk = hh >> 1;
        const int h     = hh & 1;

        // -- issue prefetch of next half into registers (hides HBM/L2 latency) --
        float4 pf[8];
        const bool has_next = (hh + 1) < nh;
        if (has_next) {
            const int nchunk = (hh + 1) >> 1, nhf = (hh + 1) & 1;
            const float* csrc = cb + (size_t)(nchunk * 128) * DDIM + nhf * 64;
#pragma unroll
            for (int v = 0; v < 8; ++v) {
                const int c  = v * 16 + ty;
                const int d0 = tx4;
                pf[v] = *(const float4*)(csrc + (size_t)c * DDIM + d0);
            }
        }

        if (h == 0) {
#pragma unroll
            for (int i = 0; i < 8; ++i)
#pragma unroll
                for (int j = 0; j < 8; ++j) acc[i][j] = 0.f;
        }

        const float* Eb = Es + (hh & 1) * (64 * 128);
#pragma unroll 4
        for (int dl = 0; dl < 64; ++dl) {
            const int d = h * 64 + dl;
            const float4 a0 = *(const float4*)(Rs + d  * 128 + rsw_(d,  ty8));
            const float4 a1 = *(const float4*)(Rs + d  * 128 + rsw_(d,  ty8 + 4));
            const float4 b0 = *(const float4*)(Eb + dl * 128 + rsw_(dl, tx4));
            const float4 b1 = *(const float4*)(Eb + dl * 128 + rsw_(dl, 64 + tx4));
            const float a[8] = {a0.x, a0.y, a0.z, a0.w, a1.x, a1.y, a1.z, a1.w};
            const float b[8] = {b0.x, b0.y, b0.z, b0.w, b1.x, b1.y, b1.z, b1.w};
#pragma unroll
            for (int i = 0; i < 8; ++i)
#pragma unroll
                for (int j = 0; j < 8; ++j)
                    acc[i][j] = fmaf(a[i], b[j], acc[i][j]);
        }

        if (h == 1) {
            // distances + running argmin for this 128-col chunk
            float nv[8];
#pragma unroll
            for (int jj = 0; jj < 8; ++jj) {
                const int col = (jj < 4) ? (tx4 + jj) : (64 + tx4 + jj - 4);
                nv[jj] = cbnorm[chunk * 128 + col];
            }
#pragma unroll
            for (int i = 0; i < 8; ++i) {
#pragma unroll
                for (int jj = 0; jj < 8; ++jj) {
                    const int col = (jj < 4) ? (tx4 + jj) : (64 + tx4 + jj - 4);
                    const int k   = chunk * 128 + col;
                    const float dist = fmaf(-2.f, acc[i][jj], nv[jj]);
                    if (dist < minv[i]) { minv[i] = dist; mink[i] = k; }
                }
            }
        }

        __syncthreads();                 // everyone done reading buf[(hh+1)&1]
        if (has_next) {
            float* En = Es + ((hh + 1) & 1) * (64 * 128);
#pragma unroll
            for (int v = 0; v < 8; ++v) {
                const int c  = v * 16 + ty;
                const int d0 = tx4;
                En[(d0 + 0) * 128 + rsw_(d0 + 0, c)] = pf[v].x;
                En[(d0 + 1) * 128 + rsw_(d0 + 1, c)] = pf[v].y;
                En[(d0 + 2) * 128 + rsw_(d0 + 2, c)] = pf[v].z;
                En[(d0 + 3) * 128 + rsw_(d0 + 3, c)] = pf[v].w;
            }
        }
        __syncthreads();
    }

    // ---- cross-thread argmin reduce (tie-break: lowest k, = jnp.argmin) ----
    float* rv = Es;                         // [128][16] candidate values
    int*   ri = (int*)(Es + 128 * 16);      // [128][16] candidate indices
    int*   kw = (int*)(Es + 128 * 32);      // [128] winners
#pragma unroll
    for (int i = 0; i < 8; ++i) {
        const int r = ty8 + i;
        rv[r * 16 + tx] = minv[i];
        ri[r * 16 + tx] = mink[i];
    }
    __syncthreads();
    if (tid < 128) {
        float bv = 3.4e38f; int bk = 0x7fffffff;
        for (int t = 0; t < 16; ++t) {
            const float v = rv[tid * 16 + t];
            const int   kk = ri[tid * 16 + t];
            if (v < bv || (v == bv && kk < bk)) { bv = v; bk = kk; }
        }
        kw[tid] = bk;
        idx_out[(size_t)(n0 + tid) * 4 + layer] = (float)bk;
        atomicAdd(&hist[bk], 1);
    }
    __syncthreads();

    // ---- residual update (replicates reference fl-arithmetic), sumsq ----
    float ssum = 0.f;
#pragma unroll
    for (int v = 0; v < 16; ++v) {
        const int flat = (v * NTHREADS + tid) * 4;
        const int r  = flat >> 7;
        const int d0 = flat & 127;
        const int k  = kw[r];
        const float4 e = *(const float4*)(cb + (size_t)k * DDIM + d0);
        float4 rsv;
        rsv.x = Rs[(d0 + 0) * 128 + rsw_(d0 + 0, r)];
        rsv.y = Rs[(d0 + 1) * 128 + rsw_(d0 + 1, r)];
        rsv.z = Rs[(d0 + 2) * 128 + rsw_(d0 + 2, r)];
        rsv.w = Rs[(d0 + 3) * 128 + rsw_(d0 + 3, r)];
        // q_st = r + (q - r); res_new = r - q_st   (match reference rounding)
        float4 rn;
        rn.x = rsv.x - (rsv.x + (e.x - rsv.x));
        rn.y = rsv.y - (rsv.y + (e.y - rsv.y));
        rn.z = rsv.z - (rsv.z + (e.z - rsv.z));
        rn.w = rsv.w - (rsv.w + (e.w - rsv.w));
        if (LAST) {
            const float4 xv = *(const float4*)(x + (size_t)(n0 + r) * DDIM + d0);
            float4 q;
            q.x = xv.x - rn.x; q.y = xv.y - rn.y; q.z = xv.z - rn.z; q.w = xv.w - rn.w;
            *(float4*)(res_out + (size_t)(n0 + r) * DDIM + d0) = q;
        } else {
            *(float4*)(res_out + (size_t)(n0 + r) * DDIM + d0) = rn;
        }
        ssum += rn.x * rn.x + rn.y * rn.y + rn.z * rn.z + rn.w * rn.w;
    }
#pragma unroll
    for (int o = 32; o; o >>= 1) ssum += __shfl_xor(ssum, o);
    __shared__ float wsum[4];
    if ((tid & 63) == 0) wsum[tid >> 6] = ssum;
    __syncthreads();
    if (tid == 0) atomicAdd(&sumsq[layer], wsum[0] + wsum[1] + wsum[2] + wsum[3]);
}

// ---------------------------------------------------------------------------
// scalars: perplexity from histogram, loss/mse from sumsq
__global__ void finalize_kernel(const int* __restrict__ hist,
                                const float* __restrict__ sumsq,
                                float* __restrict__ out)
{
    const int l   = blockIdx.x;
    const int K   = (l < 2) ? 1024 : 512;
    const int off = (l < 2) ? l * 1024 : 2048 + (l - 2) * 512;
    const int tid = threadIdx.x;
    float local = 0.f;
    for (int k = tid; k < K; k += 256) {
        const float p = (float)hist[off + k] * (1.0f / 131072.0f);
        local += p * logf(p + 1e-10f);
    }
#pragma unroll
    for (int o = 32; o; o >>= 1) local += __shfl_xor(local, o);
    __shared__ float w[4];
    if ((tid & 63) == 0) w[tid >> 6] = local;
    __syncthreads();
    if (tid == 0) {
        const float H = w[0] + w[1] + w[2] + w[3];
        out[OP + l] = expf(-H);
        const float mse = sumsq[l] * (1.0f / (131072.0f * 128.0f));
        out[OM + l] = mse;
        out[OL + l] = 1.25f * mse;
    }
}

// ---------------------------------------------------------------------------
extern "C" void kernel_launch(void* const* d_in, const int* in_sizes, int n_in,
                              void* d_out, int out_size, void* d_ws, size_t ws_size,
                              hipStream_t stream)
{
    const float* x = (const float*)d_in[0];
    const float* cbs[4] = {(const float*)d_in[1], (const float*)d_in[2],
                           (const float*)d_in[3], (const float*)d_in[4]};
    const int Ks[4]      = {1024, 1024, 512, 512};
    const int normoff[4] = {0, 1024, 2048, 2560};

    float* out  = (float*)d_out;
    float* qres = out + OQ;        // doubles as residual buffer, becomes quantized_out
    float* idxf = out + OI;

    int*   hist  = (int*)d_ws;                 // 3072 ints
    float* sumsq = (float*)d_ws + 3072;        // 4 floats
    float* norms = (float*)d_ws + 3076;        // 3072 floats

    // allow 128 KB dynamic LDS (idempotent; same work every call)
    (void)hipFuncSetAttribute(reinterpret_cast<const void*>(&vq_layer_kernel<false>),
                              hipFuncAttributeMaxDynamicSharedMemorySize, 131072);
    (void)hipFuncSetAttribute(reinterpret_cast<const void*>(&vq_layer_kernel<true>),
                              hipFuncAttributeMaxDynamicSharedMemorySize, 131072);

    // zero hist + sumsq (ws is poisoned 0xAA before every call)
    hipMemsetAsync(d_ws, 0, (3072 + 4) * sizeof(int), stream);

    for (int c = 0; c < 4; ++c)
        cbnorm_kernel<<<Ks[c] / 4, 256, 0, stream>>>(cbs[c], norms + normoff[c], Ks[c]);

    const int grid = N_ROWS / BN;  // 1024
    vq_layer_kernel<false><<<grid, NTHREADS, 131072, stream>>>(
        x,    cbs[0], norms + normoff[0], Ks[0], nullptr, qres, idxf, 0, hist + normoff[0], sumsq);
    vq_layer_kernel<false><<<grid, NTHREADS, 131072, stream>>>(
        qres, cbs[1], norms + normoff[1], Ks[1], nullptr, qres, idxf, 1, hist + normoff[1], sumsq);
    vq_layer_kernel<false><<<grid, NTHREADS, 131072, stream>>>(
        qres, cbs[2], norms + normoff[2], Ks[2], nullptr, qres, idxf, 2, hist + normoff[2], sumsq);
    vq_layer_kernel<true><<<grid, NTHREADS, 131072, stream>>>(
        qres, cbs[3], norms + normoff[3], Ks[3], x,       qres, idxf, 3, hist + normoff[3], sumsq);

    finalize_kernel<<<4, 256, 0, stream>>>(hist, sumsq, out);
}

// Round 4
// 1592.657 us; speedup vs baseline: 1.0533x; 1.0533x over previous
//
#include <hip/hip_runtime.h>
#include <math.h>

// ---------------------------------------------------------------------------
// VariableRVQ: 4-layer residual VQ, N=131072, D=128, K={1024,1024,512,512}
// d_out layout (floats): [quantized 131072*128][indices 131072*4][loss 4][perp 4][mse 4]
// ---------------------------------------------------------------------------

#define N_ROWS 131072
#define DDIM 128
#define BN 128            // rows per block
#define NTHREADS 256

#define OQ 0
#define OI 16777216
#define OL 17301504
#define OP 17301508
#define OM 17301512

// XOR swizzle (Rs only): keyed on d>>2, toggles bits 2..4 of the r index.
__device__ __forceinline__ int rsw_(int d, int r) { return r ^ (((d >> 2) & 7) << 2); }

__device__ __forceinline__ void gl16(const float* g, float* l) {
    __builtin_amdgcn_global_load_lds((const __attribute__((address_space(1))) void*)g,
                                     (__attribute__((address_space(3))) void*)l, 16, 0, 0);
}

// ---------------------------------------------------------------------------
// codebook transpose: cb [K][128] -> cbT [128][K]; coalesced stores
__global__ void transpose_cb_kernel(const float* __restrict__ cb,
                                    float* __restrict__ cbT, int K)
{
    const int tid = threadIdx.x;
    const int k  = blockIdx.x * 64 + (tid & 63);
    const int dq = tid >> 6;               // 0..3
#pragma unroll
    for (int j = 0; j < 8; ++j) {
        const int d0 = dq * 32 + j * 4;
        const float4 f = *(const float4*)(cb + (size_t)k * DDIM + d0);
        cbT[(size_t)(d0 + 0) * K + k] = f.x;
        cbT[(size_t)(d0 + 1) * K + k] = f.y;
        cbT[(size_t)(d0 + 2) * K + k] = f.z;
        cbT[(size_t)(d0 + 3) * K + k] = f.w;
    }
}

// ---------------------------------------------------------------------------
// codebook row norms: one wave per row
__global__ void cbnorm_kernel(const float* __restrict__ cb,
                              float* __restrict__ norms, int K)
{
    const int row  = blockIdx.x * 4 + (threadIdx.x >> 6);
    const int lane = threadIdx.x & 63;
    const float2 v = *(const float2*)(cb + (size_t)row * DDIM + lane * 2);
    float s = fmaf(v.x, v.x, v.y * v.y);
#pragma unroll
    for (int o = 32; o; o >>= 1) s += __shfl_xor(s, o);
    if (lane == 0) norms[row] = s;
}

// ---------------------------------------------------------------------------
// Fused: distance GEMM + argmin + gather + residual update + sumsq + histogram
// LDS: Rs [128 d][128 r] (64KB, swizzled) + Es 2 x [16 d][128 c] (16KB, linear)
template<bool LAST>
__global__ __launch_bounds__(256, 2)
void vq_layer_kernel(const float* res_in,              // [N,128] layer input residual
                     const float* __restrict__ cb,     // [K,128] row-major (gather)
                     const float* __restrict__ cbT,    // [128,K] transposed (staging)
                     const float* __restrict__ cbnorm, // [K]
                     const int K,
                     const float* __restrict__ x,      // original input (LAST only)
                     float*       res_out,             // [N,128] residual out / qout
                     float* __restrict__ idx_out,
                     const int layer,
                     int*   __restrict__ hist,
                     float* __restrict__ sumsq)
{
    extern __shared__ float lds[];
    float* Rs = lds;               // 16384 floats
    float* Es = lds + 128 * 128;   // 4096 floats (2 x 2048)

    const int tid = threadIdx.x;
    const int tx  = tid & 15, ty = tid >> 4;
    const int ty8 = ty << 3, tx4 = tx << 2;
    const int n0  = blockIdx.x * BN;

    // ---- stage residual tile: global row-major -> LDS [d][r] swizzled ----
    {
        const float* src = res_in + (size_t)n0 * DDIM;
#pragma unroll
        for (int v = 0; v < 16; ++v) {
            const int flat = (v * NTHREADS + tid) * 4;
            const int r  = flat >> 7;
            const int d0 = flat & 127;
            const float4 f = *(const float4*)(src + r * DDIM + d0);
            Rs[(d0 + 0) * 128 + rsw_(d0 + 0, r)] = f.x;
            Rs[(d0 + 1) * 128 + rsw_(d0 + 1, r)] = f.y;
            Rs[(d0 + 2) * 128 + rsw_(d0 + 2, r)] = f.z;
            Rs[(d0 + 3) * 128 + rsw_(d0 + 3, r)] = f.w;
        }
    }
    // ---- prologue: stage hh=0 (16 d x 128 c) via global_load_lds ----
    {
        float* dst = Es + ((tid >> 6) * 2) * 128;
        const float* src = cbT + (size_t)((tid >> 6) * 2 + ((tid >> 5) & 1)) * K
                               + (tid & 31) * 4;
        gl16(src, dst);
        gl16(src + (size_t)8 * K, dst + 8 * 128);
    }
    __syncthreads();   // drains vmcnt(0) before barrier (compiler-emitted)

    float minv[8];
    int   mink[8];
#pragma unroll
    for (int i = 0; i < 8; ++i) { minv[i] = 3.4e38f; mink[i] = 0; }

    const int NH = (K >> 7) * 8;   // stages of 16 d; 8 per 128-col chunk
    float acc[8][8];
    float nv[8];

    for (int hh = 0; hh < NH; ++hh) {
        const int chunk = hh >> 3;
        const int s     = hh & 7;

        // -- issue next stage's global_load_lds into the other buffer --
        if (hh + 1 < NH) {
            const int c2 = (hh + 1) >> 3, s2 = (hh + 1) & 7;
            float* dst = Es + ((hh + 1) & 1) * 2048 + ((tid >> 6) * 2) * 128;
            const float* src = cbT + (size_t)(s2 * 16 + (tid >> 6) * 2 + ((tid >> 5) & 1)) * K
                                   + c2 * 128 + (tid & 31) * 4;
            gl16(src, dst);
            gl16(src + (size_t)8 * K, dst + 8 * 128);
        }

        if (s == 0) {
#pragma unroll
            for (int i = 0; i < 8; ++i)
#pragma unroll
                for (int j = 0; j < 8; ++j) acc[i][j] = 0.f;
            // prefetch this chunk's codebook norms (used at s==7)
#pragma unroll
            for (int jj = 0; jj < 8; ++jj) {
                const int col = (jj < 4) ? (tx4 + jj) : (64 + tx4 + jj - 4);
                nv[jj] = cbnorm[chunk * 128 + col];
            }
        }

        const float* Eb = Es + (hh & 1) * 2048;
        const int dbase = s * 16;
#pragma unroll
        for (int dl = 0; dl < 16; ++dl) {
            const int d  = dbase + dl;
            const int sw = ((d >> 2) & 7) << 2;
            const float4 a0 = *(const float4*)(Rs + d * 128 + (ty8 ^ sw));
            const float4 a1 = *(const float4*)(Rs + d * 128 + ((ty8 + 4) ^ sw));
            const float4 b0 = *(const float4*)(Eb + dl * 128 + tx4);
            const float4 b1 = *(const float4*)(Eb + dl * 128 + 64 + tx4);
            const float a[8] = {a0.x, a0.y, a0.z, a0.w, a1.x, a1.y, a1.z, a1.w};
            const float b[8] = {b0.x, b0.y, b0.z, b0.w, b1.x, b1.y, b1.z, b1.w};
#pragma unroll
            for (int i = 0; i < 8; ++i)
#pragma unroll
                for (int j = 0; j < 8; ++j)
                    acc[i][j] = fmaf(a[i], b[j], acc[i][j]);
        }

        if (s == 7) {
            // distances + running argmin for this 128-col chunk
#pragma unroll
            for (int i = 0; i < 8; ++i) {
#pragma unroll
                for (int jj = 0; jj < 8; ++jj) {
                    const int col = (jj < 4) ? (tx4 + jj) : (64 + tx4 + jj - 4);
                    const int k   = chunk * 128 + col;
                    const float dist = fmaf(-2.f, acc[i][jj], nv[jj]);
                    if (dist < minv[i]) { minv[i] = dist; mink[i] = k; }
                }
            }
        }

        __syncthreads();   // buf[(hh+1)&1] loads landed; buf[hh&1] free for reuse
    }

    // ---- cross-lane argmin reduce within 16-lane groups (same ty) ----
    // tie-break: lowest k (matches jnp.argmin first-min semantics)
    int* kw = (int*)Es;                 // Es no longer needed; 128 ints
#pragma unroll
    for (int i = 0; i < 8; ++i) {
        float bv = minv[i]; int bk = mink[i];
#pragma unroll
        for (int off = 1; off < 16; off <<= 1) {
            const float ov = __shfl_xor(bv, off);
            const int   ok = __shfl_xor(bk, off);
            if (ov < bv || (ov == bv && ok < bk)) { bv = ov; bk = ok; }
        }
        if (tx == 0) {
            const int r = ty8 + i;
            kw[r] = bk;
            idx_out[(size_t)(n0 + r) * 4 + layer] = (float)bk;
            atomicAdd(&hist[bk], 1);
        }
    }
    __syncthreads();

    // ---- residual update (replicates reference fl-arithmetic), sumsq ----
    float ssum = 0.f;
#pragma unroll
    for (int v = 0; v < 16; ++v) {
        const int flat = (v * NTHREADS + tid) * 4;
        const int r  = flat >> 7;
        const int d0 = flat & 127;
        const int k  = kw[r];
        const float4 e = *(const float4*)(cb + (size_t)k * DDIM + d0);
        float4 rsv;
        rsv.x = Rs[(d0 + 0) * 128 + rsw_(d0 + 0, r)];
        rsv.y = Rs[(d0 + 1) * 128 + rsw_(d0 + 1, r)];
        rsv.z = Rs[(d0 + 2) * 128 + rsw_(d0 + 2, r)];
        rsv.w = Rs[(d0 + 3) * 128 + rsw_(d0 + 3, r)];
        // q_st = r + (q - r); res_new = r - q_st   (match reference rounding)
        float4 rn;
        rn.x = rsv.x - (rsv.x + (e.x - rsv.x));
        rn.y = rsv.y - (rsv.y + (e.y - rsv.y));
        rn.z = rsv.z - (rsv.z + (e.z - rsv.z));
        rn.w = rsv.w - (rsv.w + (e.w - rsv.w));
        if (LAST) {
            const float4 xv = *(const float4*)(x + (size_t)(n0 + r) * DDIM + d0);
            float4 q;
            q.x = xv.x - rn.x; q.y = xv.y - rn.y; q.z = xv.z - rn.z; q.w = xv.w - rn.w;
            *(float4*)(res_out + (size_t)(n0 + r) * DDIM + d0) = q;
        } else {
            *(float4*)(res_out + (size_t)(n0 + r) * DDIM + d0) = rn;
        }
        ssum += rn.x * rn.x + rn.y * rn.y + rn.z * rn.z + rn.w * rn.w;
    }
#pragma unroll
    for (int o = 32; o; o >>= 1) ssum += __shfl_xor(ssum, o);
    float* wsumP = lds + 128 * 128 + 128;     // after kw, still inside Es region
    if ((tid & 63) == 0) wsumP[tid >> 6] = ssum;
    __syncthreads();
    if (tid == 0) atomicAdd(&sumsq[layer], wsumP[0] + wsumP[1] + wsumP[2] + wsumP[3]);
}

// ---------------------------------------------------------------------------
// scalars: perplexity from histogram, loss/mse from sumsq
__global__ void finalize_kernel(const int* __restrict__ hist,
                                const float* __restrict__ sumsq,
                                float* __restrict__ out)
{
    const int l   = blockIdx.x;
    const int K   = (l < 2) ? 1024 : 512;
    const int off = (l < 2) ? l * 1024 : 2048 + (l - 2) * 512;
    const int tid = threadIdx.x;
    float local = 0.f;
    for (int k = tid; k < K; k += 256) {
        const float p = (float)hist[off + k] * (1.0f / 131072.0f);
        local += p * logf(p + 1e-10f);
    }
#pragma unroll
    for (int o = 32; o; o >>= 1) local += __shfl_xor(local, o);
    __shared__ float w[4];
    if ((tid & 63) == 0) w[tid >> 6] = local;
    __syncthreads();
    if (tid == 0) {
        const float H = w[0] + w[1] + w[2] + w[3];
        out[OP + l] = expf(-H);
        const float mse = sumsq[l] * (1.0f / (131072.0f * 128.0f));
        out[OM + l] = mse;
        out[OL + l] = 1.25f * mse;
    }
}

// ---------------------------------------------------------------------------
extern "C" void kernel_launch(void* const* d_in, const int* in_sizes, int n_in,
                              void* d_out, int out_size, void* d_ws, size_t ws_size,
                              hipStream_t stream)
{
    const float* x = (const float*)d_in[0];
    const float* cbs[4] = {(const float*)d_in[1], (const float*)d_in[2],
                           (const float*)d_in[3], (const float*)d_in[4]};
    const int Ks[4]      = {1024, 1024, 512, 512};
    const int normoff[4] = {0, 1024, 2048, 2560};
    const int cbToff[4]  = {0, 131072, 262144, 327680};   // floats within cbT pool

    float* out  = (float*)d_out;
    float* qres = out + OQ;        // residual buffer, becomes quantized_out
    float* idxf = out + OI;

    int*   hist  = (int*)d_ws;                  // 3072 ints
    float* sumsq = (float*)d_ws + 3072;         // 4 floats
    float* norms = (float*)d_ws + 3076;         // 3072 floats
    float* cbT   = (float*)d_ws + 6148;         // 393216 floats (16B aligned)

    (void)hipFuncSetAttribute(reinterpret_cast<const void*>(&vq_layer_kernel<false>),
                              hipFuncAttributeMaxDynamicSharedMemorySize, 81920);
    (void)hipFuncSetAttribute(reinterpret_cast<const void*>(&vq_layer_kernel<true>),
                              hipFuncAttributeMaxDynamicSharedMemorySize, 81920);

    hipMemsetAsync(d_ws, 0, (3072 + 4) * sizeof(int), stream);

    for (int c = 0; c < 4; ++c) {
        transpose_cb_kernel<<<Ks[c] / 64, 256, 0, stream>>>(cbs[c], cbT + cbToff[c], Ks[c]);
        cbnorm_kernel<<<Ks[c] / 4, 256, 0, stream>>>(cbs[c], norms + normoff[c], Ks[c]);
    }

    const int grid = N_ROWS / BN;  // 1024
    vq_layer_kernel<false><<<grid, NTHREADS, 81920, stream>>>(
        x,    cbs[0], cbT + cbToff[0], norms + normoff[0], Ks[0], nullptr,
        qres, idxf, 0, hist + normoff[0], sumsq);
    vq_layer_kernel<false><<<grid, NTHREADS, 81920, stream>>>(
        qres, cbs[1], cbT + cbToff[1], norms + normoff[1], Ks[1], nullptr,
        qres, idxf, 1, hist + normoff[1], sumsq);
    vq_layer_kernel<false><<<grid, NTHREADS, 81920, stream>>>(
        qres, cbs[2], cbT + cbToff[2], norms + normoff[2], Ks[2], nullptr,
        qres, idxf, 2, hist + normoff[2], sumsq);
    vq_layer_kernel<true><<<grid, NTHREADS, 81920, stream>>>(
        qres, cbs[3], cbT + cbToff[3], norms + normoff[3], Ks[3], x,
        qres, idxf, 3, hist + normoff[3], sumsq);

    finalize_kernel<<<4, 256, 0, stream>>>(hist, sumsq, out);
}

// Round 5
// 954.625 us; speedup vs baseline: 1.7573x; 1.6684x over previous
//
#include <hip/hip_runtime.h>
#include <math.h>

// ---------------------------------------------------------------------------
// VariableRVQ: 4-layer residual VQ, N=131072, D=128, K={1024,1024,512,512}
// d_out layout (floats): [quantized 131072*128][indices 131072*4][loss 4][perp 4][mse 4]
//
// Distance GEMM via fp16-split MFMA: x.e ~= hx.he + lx.he + hx.le, with
// per-row (min1,min2) tracking and exact fp32 re-scan when min2-min1 < EPS.
// ---------------------------------------------------------------------------

#define N_ROWS 131072
#define DDIM 128
#define BN 128
#define NTHREADS 256

#define OQ 0
#define OI 16777216
#define OL 17301504
#define OP 17301508
#define OM 17301512

#define RESCUE_EPS 1e-3f

typedef _Float16 f16x8 __attribute__((ext_vector_type(8)));
typedef float f32x4 __attribute__((ext_vector_type(4)));

__device__ __forceinline__ void gl16(const _Float16* g, _Float16* l) {
    __builtin_amdgcn_global_load_lds((const __attribute__((address_space(1))) void*)g,
                                     (__attribute__((address_space(3))) void*)l, 16, 0, 0);
}

// ---------------------------------------------------------------------------
// codebook fp16 split into MFMA-fragment-linear layout:
// slice s = (chunk*4 + ks) covers cols [chunk*64..+63], d [ks*32..+31].
// slice region (4096 fp16): h[nf*512 + lane*8 + i], l at +2048;
// lane = kg*16 + trow, col = chunk*64 + nf*16 + trow, d = ks*32 + kg*8 + i.
__global__ void split_cb_kernel(const float* __restrict__ cb,
                                _Float16* __restrict__ out, int K)
{
    const int idx = blockIdx.x * 256 + threadIdx.x;   // over K*128
    const int col = idx >> 7, d = idx & 127;
    const float v = cb[idx];
    const _Float16 h = (_Float16)v;
    const _Float16 l = (_Float16)(v - (float)h);
    const int c = col >> 6, nf = (col >> 4) & 3, trow = col & 15;
    const int ks = d >> 5, kg = (d >> 3) & 3, i = d & 7;
    const size_t off = (size_t)(c * 4 + ks) * 4096 + nf * 512 + (kg * 16 + trow) * 8 + i;
    out[off] = h;
    out[off + 2048] = l;
}

// ---------------------------------------------------------------------------
// codebook row norms (exact fp32): one wave per row
__global__ void cbnorm_kernel(const float* __restrict__ cb,
                              float* __restrict__ norms, int K)
{
    const int row  = blockIdx.x * 4 + (threadIdx.x >> 6);
    const int lane = threadIdx.x & 63;
    const float2 v = *(const float2*)(cb + (size_t)row * DDIM + lane * 2);
    float s = fmaf(v.x, v.x, v.y * v.y);
#pragma unroll
    for (int o = 32; o; o >>= 1) s += __shfl_xor(s, o);
    if (lane == 0) norms[row] = s;
}

// ---------------------------------------------------------------------------
// Fused layer: MFMA distance GEMM + argmin(+rescue) + residual update + stats
template<bool LAST>
__global__ __launch_bounds__(256, 2)
void vq_layer_kernel(const float* __restrict__ res_in,   // [N,128]
                     const float* __restrict__ cb,       // [K,128] fp32
                     const _Float16* __restrict__ cbS,   // split fragments
                     const float* __restrict__ cbnorm,   // [K]
                     const int K,
                     const float* __restrict__ x,        // original (LAST)
                     float* res_out,
                     float* __restrict__ idx_out,
                     const int layer,
                     int* __restrict__ hist,
                     float* __restrict__ sumsq)
{
    __shared__ _Float16 Bs[2][4096];   // double-buffered B slice (8KB each)
    __shared__ int   kw[BN];
    __shared__ int   rlist[BN];
    __shared__ int   nresc;
    __shared__ float wsum[4];

    const int tid  = threadIdx.x;
    const int w    = tid >> 6;         // wave 0..3 -> rows w*32..+31
    const int wl   = tid & 63;         // lane
    const int trow = tid & 15;         // A-row / B-col / C-col within frag
    const int tkg  = (tid >> 4) & 3;   // k-group (lane>>4)
    const int n0   = blockIdx.x * BN;

    if (tid == 0) nresc = 0;

    // ---- load + split this wave's 32 residual rows into A fragments ----
    f16x8 Ah[2][4], Al[2][4];
#pragma unroll
    for (int mf = 0; mf < 2; ++mf) {
        const int row = n0 + w * 32 + mf * 16 + trow;
        const float* rp = res_in + (size_t)row * DDIM;
#pragma unroll
        for (int ks = 0; ks < 4; ++ks) {
            const int d0 = ks * 32 + tkg * 8;
            const float4 f0 = *(const float4*)(rp + d0);
            const float4 f1 = *(const float4*)(rp + d0 + 4);
            const float vv[8] = {f0.x, f0.y, f0.z, f0.w, f1.x, f1.y, f1.z, f1.w};
#pragma unroll
            for (int i = 0; i < 8; ++i) {
                const _Float16 h = (_Float16)vv[i];
                Ah[mf][ks][i] = h;
                Al[mf][ks][i] = (_Float16)(vv[i] - (float)h);
            }
        }
    }

    // ---- prologue: stage slice 0 (linear: lane l -> base + 16*l) ----
    {
        _Float16* dst = &Bs[0][w * 1024];
        const _Float16* src = cbS + (size_t)w * 1024 + wl * 8;
        gl16(src, dst);
        gl16(src + 512, dst + 512);
    }
    __syncthreads();

    float m1v[8], m2v[8];
    int   m1k[8];
#pragma unroll
    for (int i = 0; i < 8; ++i) { m1v[i] = 3.4e38f; m2v[i] = 3.4e38f; m1k[i] = 0x7fffffff; }

    const int nchunks = K >> 6;
    const int nslices = nchunks * 4;

    for (int c = 0; c < nchunks; ++c) {
        f32x4 acc[2][4];
#pragma unroll
        for (int mf = 0; mf < 2; ++mf)
#pragma unroll
            for (int nf = 0; nf < 4; ++nf) acc[mf][nf] = f32x4{0.f, 0.f, 0.f, 0.f};

#pragma unroll
        for (int ks = 0; ks < 4; ++ks) {
            const int s = c * 4 + ks;
            const int cur = s & 1;
            if (s + 1 < nslices) {   // prefetch next slice into other buffer
                _Float16* dst = &Bs[cur ^ 1][w * 1024];
                const _Float16* src = cbS + (size_t)(s + 1) * 4096 + w * 1024 + wl * 8;
                gl16(src, dst);
                gl16(src + 512, dst + 512);
            }
#pragma unroll
            for (int nf = 0; nf < 4; ++nf) {
                const f16x8 bh = *(const f16x8*)&Bs[cur][nf * 512 + wl * 8];
                const f16x8 bl = *(const f16x8*)&Bs[cur][2048 + nf * 512 + wl * 8];
#pragma unroll
                for (int mf = 0; mf < 2; ++mf) {
                    acc[mf][nf] = __builtin_amdgcn_mfma_f32_16x16x32_f16(Ah[mf][ks], bh, acc[mf][nf], 0, 0, 0);
                    acc[mf][nf] = __builtin_amdgcn_mfma_f32_16x16x32_f16(Al[mf][ks], bh, acc[mf][nf], 0, 0, 0);
                    acc[mf][nf] = __builtin_amdgcn_mfma_f32_16x16x32_f16(Ah[mf][ks], bl, acc[mf][nf], 0, 0, 0);
                }
            }
            __syncthreads();
        }

        // ---- distances + per-lane (min1,k1,min2) tracking (registers) ----
#pragma unroll
        for (int nf = 0; nf < 4; ++nf) {
            const int col = c * 64 + nf * 16 + trow;
            const float nvv = cbnorm[col];
#pragma unroll
            for (int mf = 0; mf < 2; ++mf) {
#pragma unroll
                for (int r = 0; r < 4; ++r) {
                    const float dv = fmaf(-2.f, acc[mf][nf][r], nvv);
                    const int t8 = mf * 4 + r;
                    if (dv < m1v[t8]) { m2v[t8] = m1v[t8]; m1v[t8] = dv; m1k[t8] = col; }
                    else if (dv < m2v[t8]) m2v[t8] = dv;
                }
            }
        }
    }

    // ---- cross-lane (16-col) merge; flag near-ties for exact rescue ----
#pragma unroll
    for (int t8 = 0; t8 < 8; ++t8) {
        float v1 = m1v[t8], v2 = m2v[t8];
        int   k1 = m1k[t8];
#pragma unroll
        for (int off = 1; off < 16; off <<= 1) {
            const float ov1 = __shfl_xor(v1, off);
            const int   ok1 = __shfl_xor(k1, off);
            const float ov2 = __shfl_xor(v2, off);
            const bool take = (ov1 < v1) || (ov1 == v1 && ok1 < k1);
            const float nm2 = take ? fminf(v1, ov2) : fminf(ov1, v2);
            if (take) { v1 = ov1; k1 = ok1; }
            v2 = nm2;
        }
        if (trow == 0) {
            const int lrow = w * 32 + (t8 >> 2) * 16 + tkg * 4 + (t8 & 3);
            kw[lrow] = k1;
            if (v2 - v1 < RESCUE_EPS) {
                const int p = atomicAdd(&nresc, 1);
                rlist[p] = lrow;
            }
        }
    }
    __syncthreads();

    // ---- exact fp32 rescue: one wave scans all K for a flagged row ----
    const int nr = nresc;
    for (int j = w; j < nr; j += 4) {
        const int lrow = rlist[j];
        const float* rp = res_in + (size_t)(n0 + lrow) * DDIM;
        float best = 3.4e38f; int bestk = 0x7fffffff;
        for (int kk = wl; kk < K; kk += 64) {
            const float* ep = cb + (size_t)kk * DDIM;
            float dot = 0.f;
#pragma unroll 8
            for (int d = 0; d < DDIM; d += 4) {
                const float4 rv = *(const float4*)(rp + d);
                const float4 ev = *(const float4*)(ep + d);
                dot = fmaf(rv.x, ev.x, dot); dot = fmaf(rv.y, ev.y, dot);
                dot = fmaf(rv.z, ev.z, dot); dot = fmaf(rv.w, ev.w, dot);
            }
            const float dv = fmaf(-2.f, dot, cbnorm[kk]);
            if (dv < best) { best = dv; bestk = kk; }   // kk ascending: first-min kept
        }
#pragma unroll
        for (int off = 1; off < 64; off <<= 1) {
            const float ov = __shfl_xor(best, off);
            const int   ok = __shfl_xor(bestk, off);
            if (ov < best || (ov == best && ok < bestk)) { best = ov; bestk = ok; }
        }
        if (wl == 0) kw[lrow] = bestk;
    }
    __syncthreads();

    // ---- indices + histogram ----
    if (tid < BN) {
        const int bk = kw[tid];
        idx_out[(size_t)(n0 + tid) * 4 + layer] = (float)bk;
        atomicAdd(&hist[bk], 1);
    }

    // ---- residual update (reference fl-arithmetic), sumsq ----
    float ssum = 0.f;
#pragma unroll
    for (int v = 0; v < 16; ++v) {
        const int flat = (v * NTHREADS + tid) * 4;
        const int r  = flat >> 7;
        const int d0 = flat & 127;
        const int k  = kw[r];
        const float4 e  = *(const float4*)(cb + (size_t)k * DDIM + d0);
        const float4 rs = *(const float4*)(res_in + (size_t)(n0 + r) * DDIM + d0);
        // q_st = r + (q - r); res_new = r - q_st   (match reference rounding)
        float4 rn;
        rn.x = rs.x - (rs.x + (e.x - rs.x));
        rn.y = rs.y - (rs.y + (e.y - rs.y));
        rn.z = rs.z - (rs.z + (e.z - rs.z));
        rn.w = rs.w - (rs.w + (e.w - rs.w));
        if (LAST) {
            const float4 xv = *(const float4*)(x + (size_t)(n0 + r) * DDIM + d0);
            float4 q;
            q.x = xv.x - rn.x; q.y = xv.y - rn.y; q.z = xv.z - rn.z; q.w = xv.w - rn.w;
            *(float4*)(res_out + (size_t)(n0 + r) * DDIM + d0) = q;
        } else {
            *(float4*)(res_out + (size_t)(n0 + r) * DDIM + d0) = rn;
        }
        ssum += rn.x * rn.x + rn.y * rn.y + rn.z * rn.z + rn.w * rn.w;
    }
#pragma unroll
    for (int o = 32; o; o >>= 1) ssum += __shfl_xor(ssum, o);
    if (wl == 0) wsum[w] = ssum;
    __syncthreads();
    if (tid == 0) atomicAdd(&sumsq[layer], wsum[0] + wsum[1] + wsum[2] + wsum[3]);
}

// ---------------------------------------------------------------------------
// scalars: perplexity from histogram, loss/mse from sumsq
__global__ void finalize_kernel(const int* __restrict__ hist,
                                const float* __restrict__ sumsq,
                                float* __restrict__ out)
{
    const int l   = blockIdx.x;
    const int K   = (l < 2) ? 1024 : 512;
    const int off = (l < 2) ? l * 1024 : 2048 + (l - 2) * 512;
    const int tid = threadIdx.x;
    float local = 0.f;
    for (int k = tid; k < K; k += 256) {
        const float p = (float)hist[off + k] * (1.0f / 131072.0f);
        local += p * logf(p + 1e-10f);
    }
#pragma unroll
    for (int o = 32; o; o >>= 1) local += __shfl_xor(local, o);
    __shared__ float w[4];
    if ((tid & 63) == 0) w[tid >> 6] = local;
    __syncthreads();
    if (tid == 0) {
        const float H = w[0] + w[1] + w[2] + w[3];
        out[OP + l] = expf(-H);
        const float mse = sumsq[l] * (1.0f / (131072.0f * 128.0f));
        out[OM + l] = mse;
        out[OL + l] = 1.25f * mse;
    }
}

// ---------------------------------------------------------------------------
extern "C" void kernel_launch(void* const* d_in, const int* in_sizes, int n_in,
                              void* d_out, int out_size, void* d_ws, size_t ws_size,
                              hipStream_t stream)
{
    const float* x = (const float*)d_in[0];
    const float* cbs[4] = {(const float*)d_in[1], (const float*)d_in[2],
                           (const float*)d_in[3], (const float*)d_in[4]};
    const int Ks[4]       = {1024, 1024, 512, 512};
    const int normoff[4]  = {0, 1024, 2048, 2560};
    const size_t cbSoff[4] = {0, 262144, 524288, 655360};  // fp16 units (K*256 each)

    float* out  = (float*)d_out;
    float* qres = out + OQ;        // residual buffer, becomes quantized_out
    float* idxf = out + OI;

    int*      hist  = (int*)d_ws;                    // 3072 ints
    float*    sumsq = (float*)d_ws + 3072;           // 4 floats
    float*    norms = (float*)d_ws + 3076;           // 3072 floats
    _Float16* cbS   = (_Float16*)((float*)d_ws + 6148);  // 786432 fp16 (1.5MB)

    hipMemsetAsync(d_ws, 0, (3072 + 4) * sizeof(int), stream);

    for (int c = 0; c < 4; ++c) {
        split_cb_kernel<<<(Ks[c] * 128) / 256, 256, 0, stream>>>(cbs[c], cbS + cbSoff[c], Ks[c]);
        cbnorm_kernel<<<Ks[c] / 4, 256, 0, stream>>>(cbs[c], norms + normoff[c], Ks[c]);
    }

    const int grid = N_ROWS / BN;  // 1024
    vq_layer_kernel<false><<<grid, NTHREADS, 0, stream>>>(
        x,    cbs[0], cbS + cbSoff[0], norms + normoff[0], Ks[0], nullptr,
        qres, idxf, 0, hist + normoff[0], sumsq);
    vq_layer_kernel<false><<<grid, NTHREADS, 0, stream>>>(
        qres, cbs[1], cbS + cbSoff[1], norms + normoff[1], Ks[1], nullptr,
        qres, idxf, 1, hist + normoff[1], sumsq);
    vq_layer_kernel<false><<<grid, NTHREADS, 0, stream>>>(
        qres, cbs[2], cbS + cbSoff[2], norms + normoff[2], Ks[2], nullptr,
        qres, idxf, 2, hist + normoff[2], sumsq);
    vq_layer_kernel<true><<<grid, NTHREADS, 0, stream>>>(
        qres, cbs[3], cbS + cbSoff[3], norms + normoff[3], Ks[3], x,
        qres, idxf, 3, hist + normoff[3], sumsq);

    finalize_kernel<<<4, 256, 0, stream>>>(hist, sumsq, out);
}

// Round 7
// 778.704 us; speedup vs baseline: 2.1543x; 1.2259x over previous
//
#include <hip/hip_runtime.h>
#include <math.h>

// ---------------------------------------------------------------------------
// VariableRVQ: 4-layer residual VQ, N=131072, D=128, K={1024,1024,512,512}
// d_out layout (floats): [quantized 131072*128][indices 131072*4][loss 4][perp 4][mse 4]
//
// fp16-split MFMA distance GEMM (x.e ~= hx.he + lx.he + hx.le) with exact
// fp32 rescue of near-ties. 512-thread blocks, chunk-level double-buffered
// B staging via global_load_lds, ONE barrier per 64-col chunk.
// ---------------------------------------------------------------------------

#define N_ROWS 131072
#define DDIM 128
#define BN 256
#define NTHREADS 512

#define OQ 0
#define OI 16777216
#define OL 17301504
#define OP 17301508
#define OM 17301512

#define RESCUE_EPS 1e-3f

typedef _Float16 f16x8 __attribute__((ext_vector_type(8)));
typedef float f32x4 __attribute__((ext_vector_type(4)));

__device__ __forceinline__ void gl16(const _Float16* g, _Float16* l) {
    __builtin_amdgcn_global_load_lds((const __attribute__((address_space(1))) void*)g,
                                     (__attribute__((address_space(3))) void*)l, 16, 0, 0);
}

// ---------------------------------------------------------------------------
// codebook fp16 split, chunk-major fragment-linear layout:
// chunk c = 64 cols x 128 k, 16384 fp16 (h then l per 2048-block):
//   off = c*16384 + ks*4096 + hl*2048 + nf*512 + lane*8 + i
//   lane = kg*16 + trow;  col = c*64 + nf*16 + trow;  d = ks*32 + kg*8 + i
__global__ void split_cb_kernel(const float* __restrict__ cb,
                                _Float16* __restrict__ out, int K)
{
    const int idx = blockIdx.x * 256 + threadIdx.x;   // over K*128
    const int col = idx >> 7, d = idx & 127;
    const float v = cb[idx];
    const _Float16 h = (_Float16)v;
    const _Float16 l = (_Float16)(v - (float)h);
    const int c = col >> 6, nf = (col >> 4) & 3, trow = col & 15;
    const int ks = d >> 5, kg = (d >> 3) & 3, i = d & 7;
    const size_t off = (size_t)c * 16384 + ks * 4096 + nf * 512 + (kg * 16 + trow) * 8 + i;
    out[off] = h;
    out[off + 2048] = l;
}

// ---------------------------------------------------------------------------
// codebook row norms (exact fp32): one wave per row
__global__ void cbnorm_kernel(const float* __restrict__ cb,
                              float* __restrict__ norms, int K)
{
    const int row  = blockIdx.x * 4 + (threadIdx.x >> 6);
    const int lane = threadIdx.x & 63;
    const float2 v = *(const float2*)(cb + (size_t)row * DDIM + lane * 2);
    float s = fmaf(v.x, v.x, v.y * v.y);
#pragma unroll
    for (int o = 32; o; o >>= 1) s += __shfl_xor(s, o);
    if (lane == 0) norms[row] = s;
}

// ---------------------------------------------------------------------------
// Fused layer: MFMA distance GEMM + argmin(+rescue) + residual update + stats
template<bool LAST>
__global__ __launch_bounds__(512, 4)
void vq_layer_kernel(const float* __restrict__ res_in,   // [N,128]
                     const float* __restrict__ cb,       // [K,128] fp32
                     const _Float16* __restrict__ cbS,   // split fragments
                     const float* __restrict__ cbnorm,   // [K]
                     const int K,
                     const float* __restrict__ x,        // original (LAST)
                     float* res_out,
                     float* __restrict__ idx_out,
                     const int layer,
                     int* __restrict__ hist,
                     float* __restrict__ sumsq)
{
    extern __shared__ char smem[];
    _Float16* Bs   = (_Float16*)smem;          // 2 x 16384 fp16 (64 KB)
    int*      kw   = (int*)(smem + 65536);     // 256
    int*      rlist= (int*)(smem + 66560);     // 256
    int*      nresc= (int*)(smem + 67584);
    float*    wsum = (float*)(smem + 67600);   // 8

    const int tid  = threadIdx.x;
    const int w    = tid >> 6;         // wave 0..7 -> rows w*32..+31
    const int wl   = tid & 63;
    const int trow = tid & 15;
    const int tkg  = (tid >> 4) & 3;
    const int n0   = blockIdx.x * BN;

    if (tid == 0) *nresc = 0;

    // ---- load + split this wave's 32 residual rows into A fragments ----
    f16x8 Ah[2][4], Al[2][4];
#pragma unroll
    for (int mf = 0; mf < 2; ++mf) {
        const int row = n0 + w * 32 + mf * 16 + trow;
        const float* rp = res_in + (size_t)row * DDIM;
#pragma unroll
        for (int ks = 0; ks < 4; ++ks) {
            const int d0 = ks * 32 + tkg * 8;
            const float4 f0 = *(const float4*)(rp + d0);
            const float4 f1 = *(const float4*)(rp + d0 + 4);
            const float vv[8] = {f0.x, f0.y, f0.z, f0.w, f1.x, f1.y, f1.z, f1.w};
#pragma unroll
            for (int i = 0; i < 8; ++i) {
                const _Float16 h = (_Float16)vv[i];
                Ah[mf][ks][i] = h;
                Al[mf][ks][i] = (_Float16)(vv[i] - (float)h);
            }
        }
    }

    // ---- prologue: stage chunk 0 (32 KB, 4 rounds of 8 KB) ----
    {
        const _Float16* src = cbS + w * 512 + wl * 8;
        _Float16* dst = Bs + w * 512;
#pragma unroll
        for (int r = 0; r < 4; ++r)
            gl16(src + r * 4096, dst + r * 4096);
    }
    __syncthreads();

    float m1v[8], m2v[8];
    int   m1k[8];
#pragma unroll
    for (int i = 0; i < 8; ++i) { m1v[i] = 3.4e38f; m2v[i] = 3.4e38f; m1k[i] = 0x7fffffff; }

    const int nchunks = K >> 6;

    for (int c = 0; c < nchunks; ++c) {
        const int cur = c & 1;

        // -- issue next chunk's staging into the other buffer --
        if (c + 1 < nchunks) {
            const _Float16* src = cbS + (size_t)(c + 1) * 16384 + w * 512 + wl * 8;
            _Float16* dst = Bs + (cur ^ 1) * 16384 + w * 512;
#pragma unroll
            for (int r = 0; r < 4; ++r)
                gl16(src + r * 4096, dst + r * 4096);
        }

        f32x4 acc[2][4];
#pragma unroll
        for (int mf = 0; mf < 2; ++mf)
#pragma unroll
            for (int nf = 0; nf < 4; ++nf) acc[mf][nf] = f32x4{0.f, 0.f, 0.f, 0.f};

        const _Float16* Bb = Bs + cur * 16384;
#pragma unroll
        for (int ks = 0; ks < 4; ++ks) {
#pragma unroll
            for (int nf = 0; nf < 4; ++nf) {
                const f16x8 bh = *(const f16x8*)(Bb + ks * 4096 + nf * 512 + wl * 8);
                const f16x8 bl = *(const f16x8*)(Bb + ks * 4096 + 2048 + nf * 512 + wl * 8);
#pragma unroll
                for (int mf = 0; mf < 2; ++mf) {
                    acc[mf][nf] = __builtin_amdgcn_mfma_f32_16x16x32_f16(Ah[mf][ks], bh, acc[mf][nf], 0, 0, 0);
                    acc[mf][nf] = __builtin_amdgcn_mfma_f32_16x16x32_f16(Al[mf][ks], bh, acc[mf][nf], 0, 0, 0);
                    acc[mf][nf] = __builtin_amdgcn_mfma_f32_16x16x32_f16(Ah[mf][ks], bl, acc[mf][nf], 0, 0, 0);
                }
            }
        }

        // ---- distances + per-lane (min1,k1,min2) tracking ----
#pragma unroll
        for (int nf = 0; nf < 4; ++nf) {
            const int col = c * 64 + nf * 16 + trow;
            const float nvv = cbnorm[col];
#pragma unroll
            for (int mf = 0; mf < 2; ++mf) {
#pragma unroll
                for (int r = 0; r < 4; ++r) {
                    const float dv = fmaf(-2.f, acc[mf][nf][r], nvv);
                    const int t8 = mf * 4 + r;
                    if (dv < m1v[t8]) { m2v[t8] = m1v[t8]; m1v[t8] = dv; m1k[t8] = col; }
                    else if (dv < m2v[t8]) m2v[t8] = dv;
                }
            }
        }

        __syncthreads();   // prefetch landed; old buffer free
    }

    // ---- cross-lane (16-col) merge; flag near-ties for exact rescue ----
#pragma unroll
    for (int t8 = 0; t8 < 8; ++t8) {
        float v1 = m1v[t8], v2 = m2v[t8];
        int   k1 = m1k[t8];
#pragma unroll
        for (int off = 1; off < 16; off <<= 1) {
            const float ov1 = __shfl_xor(v1, off);
            const int   ok1 = __shfl_xor(k1, off);
            const float ov2 = __shfl_xor(v2, off);
            const bool take = (ov1 < v1) || (ov1 == v1 && ok1 < k1);
            const float nm2 = take ? fminf(v1, ov2) : fminf(ov1, v2);
            if (take) { v1 = ov1; k1 = ok1; }
            v2 = nm2;
        }
        if (trow == 0) {
            const int lrow = w * 32 + (t8 >> 2) * 16 + tkg * 4 + (t8 & 3);
            kw[lrow] = k1;
            if (v2 - v1 < RESCUE_EPS) {
                const int p = atomicAdd(nresc, 1);
                rlist[p] = lrow;
            }
        }
    }
    __syncthreads();

    // ---- exact fp32 rescue: one wave scans all K for a flagged row ----
    const int nr = *nresc;
    for (int j = w; j < nr; j += 8) {
        const int lrow = rlist[j];
        const float* rp = res_in + (size_t)(n0 + lrow) * DDIM;
        float best = 3.4e38f; int bestk = 0x7fffffff;
        for (int kk = wl; kk < K; kk += 64) {
            const float* ep = cb + (size_t)kk * DDIM;
            float dot = 0.f;
#pragma unroll 8
            for (int d = 0; d < DDIM; d += 4) {
                const float4 rv = *(const float4*)(rp + d);
                const float4 ev = *(const float4*)(ep + d);
                dot = fmaf(rv.x, ev.x, dot); dot = fmaf(rv.y, ev.y, dot);
                dot = fmaf(rv.z, ev.z, dot); dot = fmaf(rv.w, ev.w, dot);
            }
            const float dv = fmaf(-2.f, dot, cbnorm[kk]);
            if (dv < best) { best = dv; bestk = kk; }   // kk ascending: first-min
        }
#pragma unroll
        for (int off = 1; off < 64; off <<= 1) {
            const float ov = __shfl_xor(best, off);
            const int   ok = __shfl_xor(bestk, off);
            if (ov < best || (ov == best && ok < bestk)) { best = ov; bestk = ok; }
        }
        if (wl == 0) kw[lrow] = bestk;
    }
    __syncthreads();

    // ---- indices + histogram ----
    if (tid < BN) {
        const int bk = kw[tid];
        idx_out[(size_t)(n0 + tid) * 4 + layer] = (float)bk;
        atomicAdd(&hist[bk], 1);
    }

    // ---- residual update (reference fl-arithmetic), sumsq ----
    float ssum = 0.f;
#pragma unroll
    for (int v = 0; v < 16; ++v) {
        const int flat = (v * NTHREADS + tid) * 4;
        const int r  = flat >> 7;
        const int d0 = flat & 127;
        const int k  = kw[r];
        const float4 e  = *(const float4*)(cb + (size_t)k * DDIM + d0);
        const float4 rs = *(const float4*)(res_in + (size_t)(n0 + r) * DDIM + d0);
        // q_st = r + (q - r); res_new = r - q_st   (match reference rounding)
        float4 rn;
        rn.x = rs.x - (rs.x + (e.x - rs.x));
        rn.y = rs.y - (rs.y + (e.y - rs.y));
        rn.z = rs.z - (rs.z + (e.z - rs.z));
        rn.w = rs.w - (rs.w + (e.w - rs.w));
        if (LAST) {
            const float4 xv = *(const float4*)(x + (size_t)(n0 + r) * DDIM + d0);
            float4 q;
            q.x = xv.x - rn.x; q.y = xv.y - rn.y; q.z = xv.z - rn.z; q.w = xv.w - rn.w;
            *(float4*)(res_out + (size_t)(n0 + r) * DDIM + d0) = q;
        } else {
            *(float4*)(res_out + (size_t)(n0 + r) * DDIM + d0) = rn;
        }
        ssum += rn.x * rn.x + rn.y * rn.y + rn.z * rn.z + rn.w * rn.w;
    }
#pragma unroll
    for (int o = 32; o; o >>= 1) ssum += __shfl_xor(ssum, o);
    if (wl == 0) wsum[w] = ssum;
    __syncthreads();
    if (tid == 0) {
        float t = 0.f;
#pragma unroll
        for (int i = 0; i < 8; ++i) t += wsum[i];
        atomicAdd(&sumsq[layer], t);
    }
}

// ---------------------------------------------------------------------------
// scalars: perplexity from histogram, loss/mse from sumsq
__global__ void finalize_kernel(const int* __restrict__ hist,
                                const float* __restrict__ sumsq,
                                float* __restrict__ out)
{
    const int l   = blockIdx.x;
    const int K   = (l < 2) ? 1024 : 512;
    const int off = (l < 2) ? l * 1024 : 2048 + (l - 2) * 512;
    const int tid = threadIdx.x;
    float local = 0.f;
    for (int k = tid; k < K; k += 256) {
        const float p = (float)hist[off + k] * (1.0f / 131072.0f);
        local += p * logf(p + 1e-10f);
    }
#pragma unroll
    for (int o = 32; o; o >>= 1) local += __shfl_xor(local, o);
    __shared__ float w[4];
    if ((tid & 63) == 0) w[tid >> 6] = local;
    __syncthreads();
    if (tid == 0) {
        const float H = w[0] + w[1] + w[2] + w[3];
        out[OP + l] = expf(-H);
        const float mse = sumsq[l] * (1.0f / (131072.0f * 128.0f));
        out[OM + l] = mse;
        out[OL + l] = 1.25f * mse;
    }
}

// ---------------------------------------------------------------------------
extern "C" void kernel_launch(void* const* d_in, const int* in_sizes, int n_in,
                              void* d_out, int out_size, void* d_ws, size_t ws_size,
                              hipStream_t stream)
{
    const float* x = (const float*)d_in[0];
    const float* cbs[4] = {(const float*)d_in[1], (const float*)d_in[2],
                           (const float*)d_in[3], (const float*)d_in[4]};
    const int Ks[4]       = {1024, 1024, 512, 512};
    const int normoff[4]  = {0, 1024, 2048, 2560};
    const size_t cbSoff[4] = {0, 262144, 524288, 655360};  // fp16 units (K*256 each)

    float* out  = (float*)d_out;
    float* qres = out + OQ;        // residual buffer, becomes quantized_out
    float* idxf = out + OI;

    int*      hist  = (int*)d_ws;                    // 3072 ints
    float*    sumsq = (float*)d_ws + 3072;           // 4 floats
    float*    norms = (float*)d_ws + 3076;           // 3072 floats
    _Float16* cbS   = (_Float16*)((float*)d_ws + 6148);  // 786432 fp16 (1.5MB)

    const int LDSB = 67648;
    (void)hipFuncSetAttribute(reinterpret_cast<const void*>(&vq_layer_kernel<false>),
                              hipFuncAttributeMaxDynamicSharedMemorySize, LDSB);
    (void)hipFuncSetAttribute(reinterpret_cast<const void*>(&vq_layer_kernel<true>),
                              hipFuncAttributeMaxDynamicSharedMemorySize, LDSB);

    hipMemsetAsync(d_ws, 0, (3072 + 4) * sizeof(int), stream);

    for (int c = 0; c < 4; ++c) {
        split_cb_kernel<<<(Ks[c] * 128) / 256, 256, 0, stream>>>(cbs[c], cbS + cbSoff[c], Ks[c]);
        cbnorm_kernel<<<Ks[c] / 4, 256, 0, stream>>>(cbs[c], norms + normoff[c], Ks[c]);
    }

    const int grid = N_ROWS / BN;  // 512
    vq_layer_kernel<false><<<grid, NTHREADS, LDSB, stream>>>(
        x,    cbs[0], cbS + cbSoff[0], norms + normoff[0], Ks[0], nullptr,
        qres, idxf, 0, hist + normoff[0], sumsq);
    vq_layer_kernel<false><<<grid, NTHREADS, LDSB, stream>>>(
        qres, cbs[1], cbS + cbSoff[1], norms + normoff[1], Ks[1], nullptr,
        qres, idxf, 1, hist + normoff[1], sumsq);
    vq_layer_kernel<false><<<grid, NTHREADS, LDSB, stream>>>(
        qres, cbs[2], cbS + cbSoff[2], norms + normoff[2], Ks[2], nullptr,
        qres, idxf, 2, hist + normoff[2], sumsq);
    vq_layer_kernel<true><<<grid, NTHREADS, LDSB, stream>>>(
        qres, cbs[3], cbS + cbSoff[3], norms + normoff[3], Ks[3], x,
        qres, idxf, 3, hist + normoff[3], sumsq);

    finalize_kernel<<<4, 256, 0, stream>>>(hist, sumsq, out);
}